// Round 3
// baseline (6279.063 us; speedup 1.0000x reference)
//
#include <hip/hip_runtime.h>
#include <cfloat>

// Problem constants: inputs (64,256,512) fp32, emb (1024,512) fp32.
#define NROWS  16384          // 64*256
#define DIM    512
#define KC     1024
#define QELEMS (NROWS * DIM)  // 8388608
// d_out layout (fp32): [0]=loss, [1 .. QELEMS]=quantized, [1+QELEMS .. +NROWS]=indices (as float)

#define BM     128            // rows / codes per LDS tile
#define BD     32             // D-chunk
#define LDST   36             // padded LDS row stride: 144 B = 16B-aligned
#define NSPLIT 4              // K-splits (grid = 128 row-tiles * 4 = 512 blocks, 2 blocks/CU)

// ---------------- kernel 1: row sums of squares ----------------
__global__ __launch_bounds__(256) void rowsq_kernel(const float* __restrict__ M,
                                                    float* __restrict__ out) {
    int wave = threadIdx.x >> 6, lane = threadIdx.x & 63;
    int row = blockIdx.x * 4 + wave;
    const float4* Mr = (const float4*)(M + (size_t)row * DIM);
    float s = 0.f;
    #pragma unroll
    for (int i = 0; i < 2; ++i) {
        float4 v = Mr[lane + 64 * i];
        s += v.x*v.x + v.y*v.y + v.z*v.z + v.w*v.w;
    }
    #pragma unroll
    for (int off = 32; off; off >>= 1) s += __shfl_down(s, off, 64);
    if (lane == 0) out[row] = s;
}

// ---------------- kernel 2: fused distance GEMM + argmin ----------------
// Per-entry fp32 expression identical to the passing round:
//   d = fl( fl(sqx_n + sqe_k) - 2*m_nk ),  m accumulated dch->d4->xyzw order.
// Register budget: acc 64 + b4 32 + a4 4 + misc ~ 110 VGPRs. The dch loop is
// #pragma unroll 1: round-2's full unroll blew past 256 VGPRs and spilled
// 9.4 GB of scratch to HBM (the whole 2.5 ms).
__global__ __launch_bounds__(256, 2) void argmin_kernel(const float* __restrict__ A,
                                                        const float* __restrict__ E,
                                                        const float* __restrict__ esq,
                                                        const float* __restrict__ xsq,
                                                        float* __restrict__ vals,
                                                        int* __restrict__ idxs) {
    __shared__ float As[BM][LDST];
    __shared__ float Es[BM][LDST];
    const int tid = threadIdx.x;
    const int tx = tid & 15, ty = tid >> 4;       // 16x16 thread grid
    const int m0 = (blockIdx.x >> 2) * BM;
    const int split = blockIdx.x & 3;
    const int c0 = split * (KC / NSPLIT);         // 256 codes per split

    int lrow[4], lcol[4];                          // per-thread staging pattern
    #pragma unroll
    for (int q = 0; q < 4; ++q) {
        int f = tid * 4 + q;                       // 0..1023
        lrow[q] = f >> 3;
        lcol[q] = (f & 7) * 4;
    }

    float sqx8[8];
    #pragma unroll
    for (int i = 0; i < 8; ++i) sqx8[i] = xsq[m0 + i*16 + ty];

    float bv[8]; int bi[8];
    #pragma unroll
    for (int i = 0; i < 8; ++i) { bv[i] = FLT_MAX; bi[i] = 0x7fffffff; }

    for (int ct = 0; ct < KC / NSPLIT / BM; ++ct) {   // 2 code tiles per split
        const int cc = c0 + ct * BM;
        float acc[8][8];
        #pragma unroll
        for (int i = 0; i < 8; ++i)
            #pragma unroll
            for (int j = 0; j < 8; ++j) acc[i][j] = 0.f;

        #pragma unroll 1                               // DO NOT unroll: spill guard
        for (int dch = 0; dch < DIM / BD; ++dch) {
            const int dbase = dch * BD;
            #pragma unroll
            for (int q = 0; q < 4; ++q) {
                *(float4*)&As[lrow[q]][lcol[q]] =
                    *(const float4*)(A + (size_t)(m0 + lrow[q]) * DIM + dbase + lcol[q]);
                *(float4*)&Es[lrow[q]][lcol[q]] =
                    *(const float4*)(E + (size_t)(cc + lrow[q]) * DIM + dbase + lcol[q]);
            }
            __syncthreads();
            #pragma unroll
            for (int d4 = 0; d4 < BD / 4; ++d4) {
                float4 b4[8];
                #pragma unroll
                for (int j = 0; j < 8; ++j) b4[j] = *(const float4*)&Es[j*16 + tx][d4*4];
                #pragma unroll
                for (int i = 0; i < 8; ++i) {
                    float4 a4 = *(const float4*)&As[i*16 + ty][d4*4];
                    #pragma unroll
                    for (int j = 0; j < 8; ++j)
                        acc[i][j] += a4.x*b4[j].x + a4.y*b4[j].y
                                   + a4.z*b4[j].z + a4.w*b4[j].w;
                }
            }
            __syncthreads();
        }

        // scores + argmin for this 128-code tile
        float esv[8];
        #pragma unroll
        for (int j = 0; j < 8; ++j) esv[j] = esq[cc + j*16 + tx];
        #pragma unroll
        for (int i = 0; i < 8; ++i) {
            float v = FLT_MAX; int ci = 0x7fffffff;
            #pragma unroll
            for (int j = 0; j < 8; ++j) {
                float S = sqx8[i] + esv[j];       // fl(sqx + sqe)
                float s = S - 2.0f * acc[i][j];   // fl(S - 2m)
                int   c = cc + j*16 + tx;
                if (s < v || (s == v && c < ci)) { v = s; ci = c; }
            }
            #pragma unroll
            for (int m = 1; m < 16; m <<= 1) {
                float ov = __shfl_xor(v, m, 64);
                int   oc = __shfl_xor(ci, m, 64);
                if (ov < v || (ov == v && oc < ci)) { v = ov; ci = oc; }
            }
            if (v < bv[i] || (v == bv[i] && ci < bi[i])) { bv[i] = v; bi[i] = ci; }
        }
    }

    if (tx == 0) {
        #pragma unroll
        for (int i = 0; i < 8; ++i) {
            int n = m0 + i*16 + ty;
            vals[split * NROWS + n] = bv[i];
            idxs[split * NROWS + n] = bi[i];
        }
    }
}

// ---------------- kernel 3: merge K-splits, emit indices, zero loss ----------------
__global__ __launch_bounds__(256) void combine_kernel(const float* __restrict__ vals,
                                                      const int* __restrict__ idxs,
                                                      float* __restrict__ out) {
    int n = blockIdx.x * 256 + threadIdx.x;       // grid=64 -> 16384
    if (n == 0) out[0] = 0.f;
    float v = vals[n]; int idx = idxs[n];
    #pragma unroll
    for (int s = 1; s < NSPLIT; ++s) {
        float vs = vals[s * NROWS + n];
        int   is = idxs[s * NROWS + n];
        if (vs < v) { v = vs; idx = is; }         // strict < : ties keep smaller index
    }
    out[1 + QELEMS + n] = (float)idx;
}

// ---------------- kernel 4: gather quantized + loss ----------------
__global__ __launch_bounds__(256) void gather_loss_kernel(const float* __restrict__ A,
                                                          const float* __restrict__ E,
                                                          float* __restrict__ out) {
    const float* idxF = out + 1 + QELEMS;
    float* q = out + 1;
    int t = threadIdx.x;
    int row = blockIdx.x * 2 + (t >> 7);          // grid=8192, 2 rows/block
    int d4  = (t & 127) * 4;
    int idx = (int)idxF[row];
    float4 e = *(const float4*)(E + (size_t)idx * DIM + d4);
    float4 x = *(const float4*)(A + (size_t)row * DIM + d4);
    *(float4*)(q + (size_t)row * DIM + d4) = e;
    float d0 = e.x - x.x, d1 = e.y - x.y, d2 = e.z - x.z, d3 = e.w - x.w;
    float s = d0*d0 + d1*d1 + d2*d2 + d3*d3;
    #pragma unroll
    for (int off = 32; off; off >>= 1) s += __shfl_down(s, off, 64);
    __shared__ float ps[4];
    if ((t & 63) == 0) ps[t >> 6] = s;
    __syncthreads();
    if (t == 0)
        atomicAdd(out, (ps[0] + ps[1] + ps[2] + ps[3]) * (1.25f / (float)QELEMS));
}

extern "C" void kernel_launch(void* const* d_in, const int* in_sizes, int n_in,
                              void* d_out, int out_size, void* d_ws, size_t ws_size,
                              hipStream_t stream) {
    const float* A = (const float*)d_in[0];   // inputs (64,256,512)
    const float* E = (const float*)d_in[1];   // emb_weight (1024,512)
    float* out = (float*)d_out;

    float* esq  = (float*)d_ws;                    // 1024 floats
    float* xsq  = esq + KC;                        // 16384 floats
    float* vals = xsq + NROWS;                     // NSPLIT*16384 floats
    int*   idxs = (int*)(vals + NSPLIT * NROWS);   // NSPLIT*16384 ints

    rowsq_kernel<<<KC / 4,    256, 0, stream>>>(E, esq);
    rowsq_kernel<<<NROWS / 4, 256, 0, stream>>>(A, xsq);
    argmin_kernel<<<(NROWS / BM) * NSPLIT, 256, 0, stream>>>(A, E, esq, xsq, vals, idxs);
    combine_kernel<<<NROWS / 256, 256, 0, stream>>>(vals, idxs, out);
    gather_loss_kernel<<<NROWS / 2, 256, 0, stream>>>(A, E, out);
}

// Round 4
// 675.238 us; speedup vs baseline: 9.2990x; 9.2990x over previous
//
#include <hip/hip_runtime.h>
#include <cfloat>

// Problem constants: inputs (64,256,512) fp32, emb (1024,512) fp32.
#define NROWS  16384          // 64*256
#define DIM    512
#define KC     1024
#define QELEMS (NROWS * DIM)  // 8388608
// d_out layout (fp32): [0]=loss, [1 .. QELEMS]=quantized, [1+QELEMS .. +NROWS]=indices (as float)

#define BM     128            // rows per LDS tile
#define BN     64             // codes per LDS tile
#define BD     32             // D-chunk
#define LDST   36             // padded LDS row stride: 144 B = 16B-aligned
#define NSPLIT 4              // K-splits: grid = 128 row-tiles * 4 = 512 blocks

// ---------------- kernel 1: row sums of squares ----------------
__global__ __launch_bounds__(256) void rowsq_kernel(const float* __restrict__ M,
                                                    float* __restrict__ out,
                                                    float* __restrict__ loss_slot) {
    if (loss_slot && blockIdx.x == 0 && threadIdx.x == 0) *loss_slot = 0.f;
    int wave = threadIdx.x >> 6, lane = threadIdx.x & 63;
    int row = blockIdx.x * 4 + wave;
    const float4* Mr = (const float4*)(M + (size_t)row * DIM);
    float s = 0.f;
    #pragma unroll
    for (int i = 0; i < 2; ++i) {
        float4 v = Mr[lane + 64 * i];
        s += v.x*v.x + v.y*v.y + v.z*v.z + v.w*v.w;
    }
    #pragma unroll
    for (int off = 32; off; off >>= 1) s += __shfl_down(s, off, 64);
    if (lane == 0) out[row] = s;
}

// ---------------- kernel 2: fused distance GEMM + argmin ----------------
// Per-entry fp32 expression identical to the PASSING round-2 kernel:
//   d = fl( fl(sqx_n + sqe_k) - 2*m_nk ),  m accumulated dch->d4->xyzw order.
// Register budget kept deliberately low (~95 VGPRs): acc 8x4=32, b4[4]=16,
// a4=4. Round-2 fully unrolled dch -> >256 regs -> 9.4 GB spill; round-3's
// __launch_bounds__(256,2) made the allocator target 128 regs and DEMOTE the
// 64-reg acc array to scratch (19 GB of traffic, 6 ms). So: small microtile,
// plain launch_bounds, dch loop pinned to unroll 1.
__global__ __launch_bounds__(256) void argmin_kernel(const float* __restrict__ A,
                                                     const float* __restrict__ E,
                                                     const float* __restrict__ esq,
                                                     const float* __restrict__ xsq,
                                                     float* __restrict__ vals,
                                                     int* __restrict__ idxs) {
    __shared__ float As[BM][LDST];
    __shared__ float Es[BN][LDST];
    const int tid = threadIdx.x;
    const int tx = tid & 15, ty = tid >> 4;       // 16 codes x 16 rows thread grid
    const int m0 = (blockIdx.x / NSPLIT) * BM;
    const int split = blockIdx.x % NSPLIT;
    const int c0 = split * (KC / NSPLIT);         // 256 codes per split

    float sqx8[8];
    #pragma unroll
    for (int i = 0; i < 8; ++i) sqx8[i] = xsq[m0 + i*16 + ty];

    float bv[8]; int bi[8];
    #pragma unroll
    for (int i = 0; i < 8; ++i) { bv[i] = FLT_MAX; bi[i] = 0x7fffffff; }

    #pragma unroll 1
    for (int ct = 0; ct < KC / NSPLIT / BN; ++ct) {   // 4 code tiles of 64
        const int cc = c0 + ct * BN;
        float acc[8][4];
        #pragma unroll
        for (int i = 0; i < 8; ++i)
            #pragma unroll
            for (int j = 0; j < 4; ++j) acc[i][j] = 0.f;

        #pragma unroll 1                               // spill guard — do not unroll
        for (int dch = 0; dch < DIM / BD; ++dch) {
            const int dbase = dch * BD;
            // stage A-tile: 1024 float4, 4/thread; E-tile: 512 float4, 2/thread
            #pragma unroll
            for (int q = 0; q < 4; ++q) {
                int f = tid * 4 + q;
                int row = f >> 3, c4 = (f & 7) * 4;
                *(float4*)&As[row][c4] =
                    *(const float4*)(A + (size_t)(m0 + row) * DIM + dbase + c4);
            }
            #pragma unroll
            for (int q = 0; q < 2; ++q) {
                int f = tid * 2 + q;
                int row = f >> 3, c4 = (f & 7) * 4;
                *(float4*)&Es[row][c4] =
                    *(const float4*)(E + (size_t)(cc + row) * DIM + dbase + c4);
            }
            __syncthreads();
            #pragma unroll
            for (int d4 = 0; d4 < BD / 4; ++d4) {
                float4 b4[4];
                #pragma unroll
                for (int j = 0; j < 4; ++j) b4[j] = *(const float4*)&Es[j*16 + tx][d4*4];
                #pragma unroll
                for (int i = 0; i < 8; ++i) {
                    float4 a4 = *(const float4*)&As[i*16 + ty][d4*4];
                    #pragma unroll
                    for (int j = 0; j < 4; ++j)
                        acc[i][j] += a4.x*b4[j].x + a4.y*b4[j].y
                                   + a4.z*b4[j].z + a4.w*b4[j].w;
                }
            }
            __syncthreads();
        }

        // scores + argmin for this 64-code tile
        float esv[4];
        #pragma unroll
        for (int j = 0; j < 4; ++j) esv[j] = esq[cc + j*16 + tx];
        #pragma unroll
        for (int i = 0; i < 8; ++i) {
            float v = FLT_MAX; int ci = 0x7fffffff;
            #pragma unroll
            for (int j = 0; j < 4; ++j) {
                float S = sqx8[i] + esv[j];       // fl(sqx + sqe)
                float s = S - 2.0f * acc[i][j];   // fl(S - 2m)
                int   c = cc + j*16 + tx;
                if (s < v || (s == v && c < ci)) { v = s; ci = c; }
            }
            #pragma unroll
            for (int m = 1; m < 16; m <<= 1) {
                float ov = __shfl_xor(v, m, 64);
                int   oc = __shfl_xor(ci, m, 64);
                if (ov < v || (ov == v && oc < ci)) { v = ov; ci = oc; }
            }
            if (v < bv[i] || (v == bv[i] && ci < bi[i])) { bv[i] = v; bi[i] = ci; }
        }
    }

    if (tx == 0) {
        #pragma unroll
        for (int i = 0; i < 8; ++i) {
            int n = m0 + i*16 + ty;
            vals[split * NROWS + n] = bv[i];
            idxs[split * NROWS + n] = bi[i];
        }
    }
}

// ---------------- kernel 3: merge splits + gather quantized + indices + loss ----------------
__global__ __launch_bounds__(256) void finalize_kernel(const float* __restrict__ A,
                                                       const float* __restrict__ E,
                                                       const float* __restrict__ vals,
                                                       const int* __restrict__ idxs,
                                                       float* __restrict__ out) {
    float* q = out + 1;
    float* idxF = out + 1 + QELEMS;
    int t = threadIdx.x;
    int half = t >> 7;                            // 2 rows per block
    int row = blockIdx.x * 2 + half;

    __shared__ int sidx[2];
    if ((t & 127) == 0) {
        float v = vals[row]; int idx = idxs[row];
        #pragma unroll
        for (int s = 1; s < NSPLIT; ++s) {
            float vs = vals[s * NROWS + row];
            int   is = idxs[s * NROWS + row];
            if (vs < v) { v = vs; idx = is; }     // strict <: ties keep smaller index
        }
        sidx[half] = idx;
        idxF[row] = (float)idx;
    }
    __syncthreads();
    int idx = sidx[half];

    int d4 = (t & 127) * 4;
    float4 e = *(const float4*)(E + (size_t)idx * DIM + d4);
    float4 x = *(const float4*)(A + (size_t)row * DIM + d4);
    *(float4*)(q + (size_t)row * DIM + d4) = e;
    float d0 = e.x - x.x, d1 = e.y - x.y, d2 = e.z - x.z, d3 = e.w - x.w;
    float s = d0*d0 + d1*d1 + d2*d2 + d3*d3;
    #pragma unroll
    for (int off = 32; off; off >>= 1) s += __shfl_down(s, off, 64);
    __shared__ float ps[4];
    if ((t & 63) == 0) ps[t >> 6] = s;
    __syncthreads();
    if (t == 0)
        atomicAdd(out, (ps[0] + ps[1] + ps[2] + ps[3]) * (1.25f / (float)QELEMS));
}

extern "C" void kernel_launch(void* const* d_in, const int* in_sizes, int n_in,
                              void* d_out, int out_size, void* d_ws, size_t ws_size,
                              hipStream_t stream) {
    const float* A = (const float*)d_in[0];   // inputs (64,256,512)
    const float* E = (const float*)d_in[1];   // emb_weight (1024,512)
    float* out = (float*)d_out;

    float* esq  = (float*)d_ws;                    // 1024 floats
    float* xsq  = esq + KC;                        // 16384 floats
    float* vals = xsq + NROWS;                     // NSPLIT*16384 floats
    int*   idxs = (int*)(vals + NSPLIT * NROWS);   // NSPLIT*16384 ints

    rowsq_kernel<<<KC / 4,    256, 0, stream>>>(E, esq, out);  // also zeroes out[0]
    rowsq_kernel<<<NROWS / 4, 256, 0, stream>>>(A, xsq, nullptr);
    argmin_kernel<<<(NROWS / BM) * NSPLIT, 256, 0, stream>>>(A, E, esq, xsq, vals, idxs);
    finalize_kernel<<<NROWS / 2, 256, 0, stream>>>(A, E, vals, idxs, out);
}

// Round 5
// 272.329 us; speedup vs baseline: 23.0569x; 2.4795x over previous
//
#include <hip/hip_runtime.h>
#include <cfloat>

// Problem constants: inputs (64,256,512) fp32, emb (1024,512) fp32.
#define NROWS  16384          // 64*256
#define DIM    512
#define KC     1024
#define QELEMS (NROWS * DIM)  // 8388608
// d_out layout (fp32): [0]=loss, [1 .. QELEMS]=quantized, [1+QELEMS .. +NROWS]=indices (as float)

#define NSPLIT 8              // one per 128-code column block
#define LDH    40             // f16 LDS row stride (80 B = 5*16B: aligned, 2-way banks = free)

typedef float  floatx4 __attribute__((ext_vector_type(4)));
typedef _Float16 half8 __attribute__((ext_vector_type(8)));
typedef _Float16 half4 __attribute__((ext_vector_type(4)));

// ---------------- kernel 1: row sums of squares (fp32 originals) ----------------
__global__ __launch_bounds__(256) void rowsq_kernel(const float* __restrict__ M,
                                                    float* __restrict__ out,
                                                    float* __restrict__ loss_slot) {
    if (loss_slot && blockIdx.x == 0 && threadIdx.x == 0) *loss_slot = 0.f;
    int wave = threadIdx.x >> 6, lane = threadIdx.x & 63;
    int row = blockIdx.x * 4 + wave;
    const float4* Mr = (const float4*)(M + (size_t)row * DIM);
    float s = 0.f;
    #pragma unroll
    for (int i = 0; i < 2; ++i) {
        float4 v = Mr[lane + 64 * i];
        s += v.x*v.x + v.y*v.y + v.z*v.z + v.w*v.w;
    }
    #pragma unroll
    for (int off = 32; off; off >>= 1) s += __shfl_down(s, off, 64);
    if (lane == 0) out[row] = s;
}

// ---------------- kernel 2: split E into fp16 hi/lo at scale 2^16 ----------------
// e' = e*65536 keeps both eh and el well inside fp16 normal range (dodges any
// MFMA subnormal flush). Scale is an exact power of 2.
__global__ __launch_bounds__(256) void esplit_kernel(const float* __restrict__ E,
                                                     _Float16* __restrict__ eh,
                                                     _Float16* __restrict__ el) {
    int t = blockIdx.x * 256 + threadIdx.x;       // grid 512 -> 131072 float4s
    float4 v = ((const float4*)E)[t];
    float xs[4] = {v.x, v.y, v.z, v.w};
    half4 hh, hl;
    #pragma unroll
    for (int e = 0; e < 4; ++e) {
        float s = xs[e] * 65536.0f;
        _Float16 h = (_Float16)s;
        hh[e] = h;
        hl[e] = (_Float16)(s - (float)h);
    }
    ((half4*)eh)[t] = hh;
    ((half4*)el)[t] = hl;
}

// ---------------- kernel 3: MFMA distance GEMM + fused argmin ----------------
// m = x.e computed as (xh+xl).(eh+el) dropping xl.el: three fp16 MFMA products
// accumulated in fp32. x scaled 2^11, e scaled 2^16 -> m = acc * 2^-27, and the
// score keeps the PASSING rounding structure: s = fl( fl(sqx+sqe) - acc*2^-26 ).
// Split error ~5e-9 < the fp32 path's ~1.5e-8 vs numpy, so argmin-safe.
// Tile: 128 rows x 128 codes per block, 4 waves of 64x64 (4x4 MFMA subtiles).
__global__ __launch_bounds__(256) void mfma_argmin_kernel(const float* __restrict__ A,
                                                          const _Float16* __restrict__ eh,
                                                          const _Float16* __restrict__ el,
                                                          const float* __restrict__ esq,
                                                          const float* __restrict__ xsq,
                                                          float* __restrict__ vals,
                                                          int* __restrict__ idxs) {
    __shared__ _Float16 Ah[128][LDH], Al[128][LDH], Eh[128][LDH], El[128][LDH];
    __shared__ float redv[128][2];
    __shared__ int   redi[128][2];

    const int tid = threadIdx.x;
    const int lane = tid & 63, wave = tid >> 6;
    const int wm = wave >> 1, wn = wave & 1;      // 2x2 wave grid
    const int tx = lane & 15, qd = lane >> 4;
    const int bm = blockIdx.x >> 3, bn = blockIdx.x & 7;
    const int m0 = bm * 128, c0 = bn * 128;

    floatx4 acc[4][4];
    #pragma unroll
    for (int i = 0; i < 4; ++i)
        #pragma unroll
        for (int j = 0; j < 4; ++j) acc[i][j] = (floatx4){0.f, 0.f, 0.f, 0.f};

    #pragma unroll 1                               // spill guard: do not unroll K-loop
    for (int kt = 0; kt < DIM / 32; ++kt) {
        const int kb = kt * 32;
        // ---- stage: A (fp32 -> on-the-fly fp16 split, scale 2^11) + E (pre-split) ----
        #pragma unroll
        for (int it = 0; it < 2; ++it) {
            int slot = it * 256 + tid;             // 0..511
            int row = slot >> 2, kq = slot & 3;
            const float* ap = A + (size_t)(m0 + row) * DIM + kb + kq * 8;
            float4 v0 = *(const float4*)ap;
            float4 v1 = *(const float4*)(ap + 4);
            float xs[8] = {v0.x, v0.y, v0.z, v0.w, v1.x, v1.y, v1.z, v1.w};
            half8 hh, hl;
            #pragma unroll
            for (int e = 0; e < 8; ++e) {
                float xv = xs[e] * 2048.0f;
                _Float16 h = (_Float16)xv;
                hh[e] = h;
                hl[e] = (_Float16)(xv - (float)h);
            }
            *(half8*)&Ah[row][kq * 8] = hh;
            *(half8*)&Al[row][kq * 8] = hl;
            size_t eoff = (size_t)(c0 + row) * DIM + kb + kq * 8;
            *(half8*)&Eh[row][kq * 8] = *(const half8*)(eh + eoff);
            *(half8*)&El[row][kq * 8] = *(const half8*)(el + eoff);
        }
        __syncthreads();

        // ---- fragments + 3 MFMA phases (hh, hl, lh) ----
        half8 fa[4], fbh[4], fbl[4];
        #pragma unroll
        for (int i = 0; i < 4; ++i)
            fa[i] = *(const half8*)&Ah[wm * 64 + i * 16 + tx][qd * 8];
        #pragma unroll
        for (int j = 0; j < 4; ++j) {
            fbh[j] = *(const half8*)&Eh[wn * 64 + j * 16 + tx][qd * 8];
            fbl[j] = *(const half8*)&El[wn * 64 + j * 16 + tx][qd * 8];
        }
        #pragma unroll
        for (int i = 0; i < 4; ++i)
            #pragma unroll
            for (int j = 0; j < 4; ++j)
                acc[i][j] = __builtin_amdgcn_mfma_f32_16x16x32_f16(fa[i], fbh[j], acc[i][j], 0, 0, 0);
        #pragma unroll
        for (int i = 0; i < 4; ++i)
            #pragma unroll
            for (int j = 0; j < 4; ++j)
                acc[i][j] = __builtin_amdgcn_mfma_f32_16x16x32_f16(fa[i], fbl[j], acc[i][j], 0, 0, 0);
        #pragma unroll
        for (int i = 0; i < 4; ++i)                // reuse fa regs for A-lo
            fa[i] = *(const half8*)&Al[wm * 64 + i * 16 + tx][qd * 8];
        #pragma unroll
        for (int i = 0; i < 4; ++i)
            #pragma unroll
            for (int j = 0; j < 4; ++j)
                acc[i][j] = __builtin_amdgcn_mfma_f32_16x16x32_f16(fa[i], fbh[j], acc[i][j], 0, 0, 0);
        __syncthreads();
    }

    // ---- epilogue: scores + argmin over this block's 128 codes ----
    float sqe_v[4];
    #pragma unroll
    for (int j = 0; j < 4; ++j) sqe_v[j] = esq[c0 + wn * 64 + j * 16 + tx];
    #pragma unroll
    for (int i = 0; i < 4; ++i) {
        #pragma unroll
        for (int r = 0; r < 4; ++r) {
            int rl = wm * 64 + i * 16 + qd * 4 + r;        // row_local (C/D: m = qd*4+reg)
            float sx = xsq[m0 + rl];
            float bvv = FLT_MAX; int bii = 0x7fffffff;
            #pragma unroll
            for (int j = 0; j < 4; ++j) {
                float S = sx + sqe_v[j];                   // fl(sqx + sqe)
                float s = S - acc[i][j][r] * (1.0f / 67108864.0f);  // fl(S - 2m), 2m exact
                int c = c0 + wn * 64 + j * 16 + tx;
                if (s < bvv || (s == bvv && c < bii)) { bvv = s; bii = c; }
            }
            #pragma unroll
            for (int md = 1; md < 16; md <<= 1) {          // reduce across tx (same qd)
                float ov = __shfl_xor(bvv, md, 64);
                int   oc = __shfl_xor(bii, md, 64);
                if (ov < bvv || (ov == bvv && oc < bii)) { bvv = ov; bii = oc; }
            }
            if (tx == 0) { redv[rl][wn] = bvv; redi[rl][wn] = bii; }
        }
    }
    __syncthreads();
    if (tid < 128) {
        float v0 = redv[tid][0], v1 = redv[tid][1];
        int   i0 = redi[tid][0], i1 = redi[tid][1];
        vals[bn * NROWS + m0 + tid] = (v1 < v0) ? v1 : v0;   // tie -> wn0 (smaller col)
        idxs[bn * NROWS + m0 + tid] = (v1 < v0) ? i1 : i0;
    }
}

// ---------------- kernel 4: merge splits + gather quantized + indices + loss ----------------
__global__ __launch_bounds__(256) void finalize_kernel(const float* __restrict__ A,
                                                       const float* __restrict__ E,
                                                       const float* __restrict__ vals,
                                                       const int* __restrict__ idxs,
                                                       float* __restrict__ out) {
    float* q = out + 1;
    float* idxF = out + 1 + QELEMS;
    int t = threadIdx.x;
    int half_ = t >> 7;                           // 2 rows per block
    int row = blockIdx.x * 2 + half_;

    __shared__ int sidx[2];
    if ((t & 127) == 0) {
        float v = vals[row]; int idx = idxs[row];
        #pragma unroll
        for (int s = 1; s < NSPLIT; ++s) {
            float vs = vals[s * NROWS + row];
            int   is = idxs[s * NROWS + row];
            if (vs < v) { v = vs; idx = is; }     // strict <: ties keep smaller index
        }
        sidx[half_] = idx;
        idxF[row] = (float)idx;
    }
    __syncthreads();
    int idx = sidx[half_];

    int d4 = (t & 127) * 4;
    float4 e = *(const float4*)(E + (size_t)idx * DIM + d4);
    float4 x = *(const float4*)(A + (size_t)row * DIM + d4);
    *(float4*)(q + (size_t)row * DIM + d4) = e;
    float d0 = e.x - x.x, d1 = e.y - x.y, d2 = e.z - x.z, d3 = e.w - x.w;
    float s = d0*d0 + d1*d1 + d2*d2 + d3*d3;
    #pragma unroll
    for (int off = 32; off; off >>= 1) s += __shfl_down(s, off, 64);
    __shared__ float ps[4];
    if ((t & 63) == 0) ps[t >> 6] = s;
    __syncthreads();
    if (t == 0)
        atomicAdd(out, (ps[0] + ps[1] + ps[2] + ps[3]) * (1.25f / (float)QELEMS));
}

extern "C" void kernel_launch(void* const* d_in, const int* in_sizes, int n_in,
                              void* d_out, int out_size, void* d_ws, size_t ws_size,
                              hipStream_t stream) {
    const float* A = (const float*)d_in[0];   // inputs (64,256,512)
    const float* E = (const float*)d_in[1];   // emb_weight (1024,512)
    float* out = (float*)d_out;

    float*    esq  = (float*)d_ws;                      // 1024
    float*    xsq  = esq + KC;                          // 16384
    float*    vals = xsq + NROWS;                       // 8*16384
    int*      idxs = (int*)(vals + NSPLIT * NROWS);     // 8*16384
    _Float16* eh   = (_Float16*)(idxs + NSPLIT * NROWS);// 1024*512
    _Float16* el   = eh + (size_t)KC * DIM;             // 1024*512

    rowsq_kernel<<<KC / 4,    256, 0, stream>>>(E, esq, out);   // also zeroes out[0]
    rowsq_kernel<<<NROWS / 4, 256, 0, stream>>>(A, xsq, nullptr);
    esplit_kernel<<<KC * DIM / 4 / 256, 256, 0, stream>>>(E, eh, el);
    mfma_argmin_kernel<<<(NROWS / 128) * NSPLIT, 256, 0, stream>>>(A, eh, el, esq, xsq, vals, idxs);
    finalize_kernel<<<NROWS / 2, 256, 0, stream>>>(A, E, vals, idxs, out);
}

// Round 6
// 192.875 us; speedup vs baseline: 32.5551x; 1.4119x over previous
//
#include <hip/hip_runtime.h>
#include <cfloat>

// Problem constants: inputs (64,256,512) fp32, emb (1024,512) fp32.
#define NROWS  16384          // 64*256
#define DIM    512
#define KC     1024
#define QELEMS (NROWS * DIM)  // 8388608
// d_out layout (fp32): [0]=loss, [1 .. QELEMS]=quantized, [1+QELEMS .. +NROWS]=indices (as float)

#define NSPLIT 8              // one per 128-code column block
#define LDH    40             // f16 LDS row stride (80 B: 16B-aligned, 2-way banks = free)

typedef float  floatx4 __attribute__((ext_vector_type(4)));
typedef _Float16 half8 __attribute__((ext_vector_type(8)));
typedef _Float16 half4 __attribute__((ext_vector_type(4)));

// ---------------- kernel 1: row sums of squares (fp32 originals) ----------------
// UNCHANGED from the passing rounds: xsq/esq rounding trees are part of the
// verified score-rounding structure — do not touch.
__global__ __launch_bounds__(256) void rowsq_kernel(const float* __restrict__ M,
                                                    float* __restrict__ out,
                                                    float* __restrict__ loss_slot) {
    if (loss_slot && blockIdx.x == 0 && threadIdx.x == 0) *loss_slot = 0.f;
    int wave = threadIdx.x >> 6, lane = threadIdx.x & 63;
    int row = blockIdx.x * 4 + wave;
    const float4* Mr = (const float4*)(M + (size_t)row * DIM);
    float s = 0.f;
    #pragma unroll
    for (int i = 0; i < 2; ++i) {
        float4 v = Mr[lane + 64 * i];
        s += v.x*v.x + v.y*v.y + v.z*v.z + v.w*v.w;
    }
    #pragma unroll
    for (int off = 32; off; off >>= 1) s += __shfl_down(s, off, 64);
    if (lane == 0) out[row] = s;
}

// ---------------- kernel 2: generic fp32 -> fp16 hi/lo split ----------------
// Elementwise and bit-exact identical to the round-5 in-kernel conversion:
// s = x*scale (exact pow2); hi = (f16)s; lo = (f16)(s - (float)hi).
__global__ __launch_bounds__(256) void split_kernel(const float* __restrict__ M,
                                                    _Float16* __restrict__ hi,
                                                    _Float16* __restrict__ lo,
                                                    float scale) {
    int t = blockIdx.x * 256 + threadIdx.x;
    float4 v = ((const float4*)M)[t];
    float xs[4] = {v.x, v.y, v.z, v.w};
    half4 hh, hl;
    #pragma unroll
    for (int e = 0; e < 4; ++e) {
        float s = xs[e] * scale;
        _Float16 h = (_Float16)s;
        hh[e] = h;
        hl[e] = (_Float16)(s - (float)h);
    }
    ((half4*)hi)[t] = hh;
    ((half4*)lo)[t] = hl;
}

// ---------------- kernel 3 (fast path): MFMA distance GEMM + fused argmin ----------------
// A and E both pre-split (x scaled 2^11, e scaled 2^16); m = acc * 2^-27.
// Score keeps the PASSING rounding structure: s = fl( fl(sqx+sqe) - acc*2^-26 ).
// Staging is pure 16B copies — the 8x-redundant fp32->fp16 conversion VALU work
// from round 5 is gone (moved to split_kernel, done once).
__global__ __launch_bounds__(256) void mfma_argmin_kernel(const _Float16* __restrict__ ah,
                                                          const _Float16* __restrict__ al,
                                                          const _Float16* __restrict__ eh,
                                                          const _Float16* __restrict__ el,
                                                          const float* __restrict__ esq,
                                                          const float* __restrict__ xsq,
                                                          float* __restrict__ vals,
                                                          int* __restrict__ idxs) {
    __shared__ _Float16 Ah[128][LDH], Al[128][LDH], Eh[128][LDH], El[128][LDH];
    __shared__ float redv[128][2];
    __shared__ int   redi[128][2];

    const int tid = threadIdx.x;
    const int lane = tid & 63, wave = tid >> 6;
    const int wm = wave >> 1, wn = wave & 1;      // 2x2 wave grid
    const int tx = lane & 15, qd = lane >> 4;
    const int bm = blockIdx.x >> 3, bn = blockIdx.x & 7;
    const int m0 = bm * 128, c0 = bn * 128;

    floatx4 acc[4][4];
    #pragma unroll
    for (int i = 0; i < 4; ++i)
        #pragma unroll
        for (int j = 0; j < 4; ++j) acc[i][j] = (floatx4){0.f, 0.f, 0.f, 0.f};

    #pragma unroll 1                               // spill guard: do not unroll K-loop
    for (int kt = 0; kt < DIM / 32; ++kt) {
        const int kb = kt * 32;
        #pragma unroll
        for (int it = 0; it < 2; ++it) {
            int slot = it * 256 + tid;             // 0..511
            int row = slot >> 2, kq = slot & 3;
            size_t aoff = (size_t)(m0 + row) * DIM + kb + kq * 8;
            *(half8*)&Ah[row][kq * 8] = *(const half8*)(ah + aoff);
            *(half8*)&Al[row][kq * 8] = *(const half8*)(al + aoff);
            size_t eoff = (size_t)(c0 + row) * DIM + kb + kq * 8;
            *(half8*)&Eh[row][kq * 8] = *(const half8*)(eh + eoff);
            *(half8*)&El[row][kq * 8] = *(const half8*)(el + eoff);
        }
        __syncthreads();

        half8 fa[4], fbh[4], fbl[4];
        #pragma unroll
        for (int i = 0; i < 4; ++i)
            fa[i] = *(const half8*)&Ah[wm * 64 + i * 16 + tx][qd * 8];
        #pragma unroll
        for (int j = 0; j < 4; ++j) {
            fbh[j] = *(const half8*)&Eh[wn * 64 + j * 16 + tx][qd * 8];
            fbl[j] = *(const half8*)&El[wn * 64 + j * 16 + tx][qd * 8];
        }
        #pragma unroll
        for (int i = 0; i < 4; ++i)
            #pragma unroll
            for (int j = 0; j < 4; ++j)
                acc[i][j] = __builtin_amdgcn_mfma_f32_16x16x32_f16(fa[i], fbh[j], acc[i][j], 0, 0, 0);
        #pragma unroll
        for (int i = 0; i < 4; ++i)
            #pragma unroll
            for (int j = 0; j < 4; ++j)
                acc[i][j] = __builtin_amdgcn_mfma_f32_16x16x32_f16(fa[i], fbl[j], acc[i][j], 0, 0, 0);
        #pragma unroll
        for (int i = 0; i < 4; ++i)                // reuse fa regs for A-lo
            fa[i] = *(const half8*)&Al[wm * 64 + i * 16 + tx][qd * 8];
        #pragma unroll
        for (int i = 0; i < 4; ++i)
            #pragma unroll
            for (int j = 0; j < 4; ++j)
                acc[i][j] = __builtin_amdgcn_mfma_f32_16x16x32_f16(fa[i], fbh[j], acc[i][j], 0, 0, 0);
        __syncthreads();
    }

    // ---- epilogue: scores + argmin over this block's 128 codes (identical to round 5) ----
    float sqe_v[4];
    #pragma unroll
    for (int j = 0; j < 4; ++j) sqe_v[j] = esq[c0 + wn * 64 + j * 16 + tx];
    #pragma unroll
    for (int i = 0; i < 4; ++i) {
        #pragma unroll
        for (int r = 0; r < 4; ++r) {
            int rl = wm * 64 + i * 16 + qd * 4 + r;        // C/D: row = qd*4+reg
            float sx = xsq[m0 + rl];
            float bvv = FLT_MAX; int bii = 0x7fffffff;
            #pragma unroll
            for (int j = 0; j < 4; ++j) {
                float S = sx + sqe_v[j];                   // fl(sqx + sqe)
                float s = S - acc[i][j][r] * (1.0f / 67108864.0f);  // fl(S - 2m)
                int c = c0 + wn * 64 + j * 16 + tx;
                if (s < bvv || (s == bvv && c < bii)) { bvv = s; bii = c; }
            }
            #pragma unroll
            for (int md = 1; md < 16; md <<= 1) {
                float ov = __shfl_xor(bvv, md, 64);
                int   oc = __shfl_xor(bii, md, 64);
                if (ov < bvv || (ov == bvv && oc < bii)) { bvv = ov; bii = oc; }
            }
            if (tx == 0) { redv[rl][wn] = bvv; redi[rl][wn] = bii; }
        }
    }
    __syncthreads();
    if (tid < 128) {
        float v0 = redv[tid][0], v1 = redv[tid][1];
        int   i0 = redi[tid][0], i1 = redi[tid][1];
        vals[bn * NROWS + m0 + tid] = (v1 < v0) ? v1 : v0;
        idxs[bn * NROWS + m0 + tid] = (v1 < v0) ? i1 : i0;
    }
}

// ---------------- kernel 3 (fallback, ws too small): round-5 on-the-fly A split ----------------
__global__ __launch_bounds__(256) void mfma_argmin_conv_kernel(const float* __restrict__ A,
                                                               const _Float16* __restrict__ eh,
                                                               const _Float16* __restrict__ el,
                                                               const float* __restrict__ esq,
                                                               const float* __restrict__ xsq,
                                                               float* __restrict__ vals,
                                                               int* __restrict__ idxs) {
    __shared__ _Float16 Ah[128][LDH], Al[128][LDH], Eh[128][LDH], El[128][LDH];
    __shared__ float redv[128][2];
    __shared__ int   redi[128][2];
    const int tid = threadIdx.x;
    const int lane = tid & 63, wave = tid >> 6;
    const int wm = wave >> 1, wn = wave & 1;
    const int tx = lane & 15, qd = lane >> 4;
    const int bm = blockIdx.x >> 3, bn = blockIdx.x & 7;
    const int m0 = bm * 128, c0 = bn * 128;

    floatx4 acc[4][4];
    #pragma unroll
    for (int i = 0; i < 4; ++i)
        #pragma unroll
        for (int j = 0; j < 4; ++j) acc[i][j] = (floatx4){0.f, 0.f, 0.f, 0.f};

    #pragma unroll 1
    for (int kt = 0; kt < DIM / 32; ++kt) {
        const int kb = kt * 32;
        #pragma unroll
        for (int it = 0; it < 2; ++it) {
            int slot = it * 256 + tid;
            int row = slot >> 2, kq = slot & 3;
            const float* ap = A + (size_t)(m0 + row) * DIM + kb + kq * 8;
            float4 v0 = *(const float4*)ap;
            float4 v1 = *(const float4*)(ap + 4);
            float xs[8] = {v0.x, v0.y, v0.z, v0.w, v1.x, v1.y, v1.z, v1.w};
            half8 hh, hl;
            #pragma unroll
            for (int e = 0; e < 8; ++e) {
                float xv = xs[e] * 2048.0f;
                _Float16 h = (_Float16)xv;
                hh[e] = h;
                hl[e] = (_Float16)(xv - (float)h);
            }
            *(half8*)&Ah[row][kq * 8] = hh;
            *(half8*)&Al[row][kq * 8] = hl;
            size_t eoff = (size_t)(c0 + row) * DIM + kb + kq * 8;
            *(half8*)&Eh[row][kq * 8] = *(const half8*)(eh + eoff);
            *(half8*)&El[row][kq * 8] = *(const half8*)(el + eoff);
        }
        __syncthreads();
        half8 fa[4], fbh[4], fbl[4];
        #pragma unroll
        for (int i = 0; i < 4; ++i)
            fa[i] = *(const half8*)&Ah[wm * 64 + i * 16 + tx][qd * 8];
        #pragma unroll
        for (int j = 0; j < 4; ++j) {
            fbh[j] = *(const half8*)&Eh[wn * 64 + j * 16 + tx][qd * 8];
            fbl[j] = *(const half8*)&El[wn * 64 + j * 16 + tx][qd * 8];
        }
        #pragma unroll
        for (int i = 0; i < 4; ++i)
            #pragma unroll
            for (int j = 0; j < 4; ++j)
                acc[i][j] = __builtin_amdgcn_mfma_f32_16x16x32_f16(fa[i], fbh[j], acc[i][j], 0, 0, 0);
        #pragma unroll
        for (int i = 0; i < 4; ++i)
            #pragma unroll
            for (int j = 0; j < 4; ++j)
                acc[i][j] = __builtin_amdgcn_mfma_f32_16x16x32_f16(fa[i], fbl[j], acc[i][j], 0, 0, 0);
        #pragma unroll
        for (int i = 0; i < 4; ++i)
            fa[i] = *(const half8*)&Al[wm * 64 + i * 16 + tx][qd * 8];
        #pragma unroll
        for (int i = 0; i < 4; ++i)
            #pragma unroll
            for (int j = 0; j < 4; ++j)
                acc[i][j] = __builtin_amdgcn_mfma_f32_16x16x32_f16(fa[i], fbh[j], acc[i][j], 0, 0, 0);
        __syncthreads();
    }

    float sqe_v[4];
    #pragma unroll
    for (int j = 0; j < 4; ++j) sqe_v[j] = esq[c0 + wn * 64 + j * 16 + tx];
    #pragma unroll
    for (int i = 0; i < 4; ++i) {
        #pragma unroll
        for (int r = 0; r < 4; ++r) {
            int rl = wm * 64 + i * 16 + qd * 4 + r;
            float sx = xsq[m0 + rl];
            float bvv = FLT_MAX; int bii = 0x7fffffff;
            #pragma unroll
            for (int j = 0; j < 4; ++j) {
                float S = sx + sqe_v[j];
                float s = S - acc[i][j][r] * (1.0f / 67108864.0f);
                int c = c0 + wn * 64 + j * 16 + tx;
                if (s < bvv || (s == bvv && c < bii)) { bvv = s; bii = c; }
            }
            #pragma unroll
            for (int md = 1; md < 16; md <<= 1) {
                float ov = __shfl_xor(bvv, md, 64);
                int   oc = __shfl_xor(bii, md, 64);
                if (ov < bvv || (ov == bvv && oc < bii)) { bvv = ov; bii = oc; }
            }
            if (tx == 0) { redv[rl][wn] = bvv; redi[rl][wn] = bii; }
        }
    }
    __syncthreads();
    if (tid < 128) {
        float v0 = redv[tid][0], v1 = redv[tid][1];
        int   i0 = redi[tid][0], i1 = redi[tid][1];
        vals[bn * NROWS + m0 + tid] = (v1 < v0) ? v1 : v0;
        idxs[bn * NROWS + m0 + tid] = (v1 < v0) ? i1 : i0;
    }
}

// ---------------- kernel 4: merge splits + gather + indices + loss ----------------
// 64 rows per block, grid 256 -> only 256 same-address atomics (round 5's 8192
// same-address atomics serialized into the whole 109 us kernel time).
__global__ __launch_bounds__(256) void finalize_kernel(const float* __restrict__ A,
                                                       const float* __restrict__ E,
                                                       const float* __restrict__ vals,
                                                       const int* __restrict__ idxs,
                                                       float* __restrict__ out) {
    float* q = out + 1;
    float* idxF = out + 1 + QELEMS;
    const int tid = threadIdx.x;
    const int r0 = blockIdx.x * 64;

    __shared__ int sidx[64];
    if (tid < 64) {                               // wave 0: merge 8 splits, coalesced
        int n = r0 + tid;
        float v = vals[n]; int idx = idxs[n];
        #pragma unroll
        for (int s = 1; s < NSPLIT; ++s) {
            float vs = vals[s * NROWS + n];
            int   is = idxs[s * NROWS + n];
            if (vs < v) { v = vs; idx = is; }     // strict <: ties keep smaller index
        }
        sidx[tid] = idx;
        idxF[n] = (float)idx;
    }
    __syncthreads();

    float sacc = 0.f;
    #pragma unroll 1
    for (int it = 0; it < 32; ++it) {             // 64 rows * 128 float4 = 8192 slots
        int flat = it * 256 + tid;
        int row = flat >> 7;
        int d4  = (flat & 127) * 4;
        int idx = sidx[row];
        float4 e = *(const float4*)(E + (size_t)idx * DIM + d4);
        float4 x = *(const float4*)(A + (size_t)(r0 + row) * DIM + d4);
        *(float4*)(q + (size_t)(r0 + row) * DIM + d4) = e;
        float d0 = e.x - x.x, d1 = e.y - x.y, d2 = e.z - x.z, d3 = e.w - x.w;
        sacc += d0*d0 + d1*d1 + d2*d2 + d3*d3;
    }
    #pragma unroll
    for (int off = 32; off; off >>= 1) sacc += __shfl_down(sacc, off, 64);
    __shared__ float ps[4];
    if ((tid & 63) == 0) ps[tid >> 6] = sacc;
    __syncthreads();
    if (tid == 0)
        atomicAdd(out, (ps[0] + ps[1] + ps[2] + ps[3]) * (1.25f / (float)QELEMS));
}

extern "C" void kernel_launch(void* const* d_in, const int* in_sizes, int n_in,
                              void* d_out, int out_size, void* d_ws, size_t ws_size,
                              hipStream_t stream) {
    const float* A = (const float*)d_in[0];   // inputs (64,256,512)
    const float* E = (const float*)d_in[1];   // emb_weight (1024,512)
    float* out = (float*)d_out;

    float*    esq  = (float*)d_ws;                       // 1024
    float*    xsq  = esq + KC;                           // 16384
    float*    vals = xsq + NROWS;                        // 8*16384
    int*      idxs = (int*)(vals + NSPLIT * NROWS);      // 8*16384
    _Float16* eh   = (_Float16*)(idxs + NSPLIT * NROWS); // 1024*512
    _Float16* el   = eh + (size_t)KC * DIM;
    _Float16* ah   = el + (size_t)KC * DIM;              // 16384*512 (fast path only)
    _Float16* al   = ah + (size_t)NROWS * DIM;

    size_t need_fast = (size_t)((char*)(al + (size_t)NROWS * DIM) - (char*)d_ws);

    rowsq_kernel<<<KC / 4,    256, 0, stream>>>(E, esq, out);   // also zeroes out[0]
    rowsq_kernel<<<NROWS / 4, 256, 0, stream>>>(A, xsq, nullptr);
    split_kernel<<<KC * DIM / 4 / 256, 256, 0, stream>>>(E, eh, el, 65536.0f);

    if (ws_size >= need_fast) {
        split_kernel<<<NROWS * DIM / 4 / 256, 256, 0, stream>>>(A, ah, al, 2048.0f);
        mfma_argmin_kernel<<<(NROWS / 128) * NSPLIT, 256, 0, stream>>>(
            ah, al, eh, el, esq, xsq, vals, idxs);
    } else {
        mfma_argmin_conv_kernel<<<(NROWS / 128) * NSPLIT, 256, 0, stream>>>(
            A, eh, el, esq, xsq, vals, idxs);
    }
    finalize_kernel<<<NROWS / 64, 256, 0, stream>>>(A, E, vals, idxs, out);
}

// Round 7
// 190.804 us; speedup vs baseline: 32.9085x; 1.0109x over previous
//
#include <hip/hip_runtime.h>
#include <cfloat>

// Problem constants: inputs (64,256,512) fp32, emb (1024,512) fp32.
#define NROWS  16384          // 64*256
#define DIM    512
#define KC     1024
#define QELEMS (NROWS * DIM)  // 8388608
// d_out layout (fp32): [0]=loss, [1 .. QELEMS]=quantized, [1+QELEMS .. +NROWS]=indices (as float)

#define NSPLIT 8              // one per 128-code column block

typedef float  floatx4 __attribute__((ext_vector_type(4)));
typedef _Float16 half8 __attribute__((ext_vector_type(8)));
typedef _Float16 half4 __attribute__((ext_vector_type(4)));

// async global->LDS, 16 B per lane, dest = wave-uniform base + lane*16
__device__ __forceinline__ void gl_lds16(const _Float16* g, void* l) {
    __builtin_amdgcn_global_load_lds(
        (const __attribute__((address_space(1))) unsigned int*)g,
        (__attribute__((address_space(3))) unsigned int*)l,
        16, 0, 0);
}

// ---------------- kernel 1: fused rowsq + fp16 hi/lo split (A), init packed ----------------
// rowsq tree + split math VERBATIM from the passing rounds (part of the verified
// rounding structure). One A read instead of two.
__global__ __launch_bounds__(256) void prep_a_kernel(const float* __restrict__ A,
                                                     float* __restrict__ xsq,
                                                     _Float16* __restrict__ ah,
                                                     _Float16* __restrict__ al,
                                                     unsigned long long* __restrict__ packed,
                                                     float* __restrict__ out) {
    if (blockIdx.x == 0 && threadIdx.x == 0) out[0] = 0.f;
    int wave = threadIdx.x >> 6, lane = threadIdx.x & 63;
    int row = blockIdx.x * 4 + wave;
    const float4* Mr = (const float4*)(A + (size_t)row * DIM);
    float4 va = Mr[lane];
    float4 vb = Mr[lane + 64];
    float s = 0.f;
    s += va.x*va.x + va.y*va.y + va.z*va.z + va.w*va.w;   // same tree as rowsq i=0
    s += vb.x*vb.x + vb.y*vb.y + vb.z*vb.z + vb.w*vb.w;   // i=1
    #pragma unroll
    for (int off = 32; off; off >>= 1) s += __shfl_down(s, off, 64);
    if (lane == 0) { xsq[row] = s; packed[row] = ~0ULL; }

    // split (scale 2^11), elementwise identical to the passing split_kernel
    float xa[4] = {va.x, va.y, va.z, va.w}, xb[4] = {vb.x, vb.y, vb.z, vb.w};
    half4 ha, la, hb, lb;
    #pragma unroll
    for (int e = 0; e < 4; ++e) {
        float t = xa[e] * 2048.0f;
        _Float16 h = (_Float16)t;
        ha[e] = h; la[e] = (_Float16)(t - (float)h);
        t = xb[e] * 2048.0f;
        h = (_Float16)t;
        hb[e] = h; lb[e] = (_Float16)(t - (float)h);
    }
    _Float16* ar = ah + (size_t)row * DIM;
    _Float16* lr = al + (size_t)row * DIM;
    ((half4*)ar)[lane]      = ha;
    ((half4*)lr)[lane]      = la;
    ((half4*)ar)[lane + 64] = hb;
    ((half4*)lr)[lane + 64] = lb;
}

// ---------------- kernel 2: fused rowsq + split (E, scale 2^16) ----------------
__global__ __launch_bounds__(256) void prep_e_kernel(const float* __restrict__ E,
                                                     float* __restrict__ esq,
                                                     _Float16* __restrict__ eh,
                                                     _Float16* __restrict__ el) {
    int wave = threadIdx.x >> 6, lane = threadIdx.x & 63;
    int row = blockIdx.x * 4 + wave;
    const float4* Mr = (const float4*)(E + (size_t)row * DIM);
    float4 va = Mr[lane];
    float4 vb = Mr[lane + 64];
    float s = 0.f;
    s += va.x*va.x + va.y*va.y + va.z*va.z + va.w*va.w;
    s += vb.x*vb.x + vb.y*vb.y + vb.z*vb.z + vb.w*vb.w;
    #pragma unroll
    for (int off = 32; off; off >>= 1) s += __shfl_down(s, off, 64);
    if (lane == 0) esq[row] = s;

    float xa[4] = {va.x, va.y, va.z, va.w}, xb[4] = {vb.x, vb.y, vb.z, vb.w};
    half4 ha, la, hb, lb;
    #pragma unroll
    for (int e = 0; e < 4; ++e) {
        float t = xa[e] * 65536.0f;
        _Float16 h = (_Float16)t;
        ha[e] = h; la[e] = (_Float16)(t - (float)h);
        t = xb[e] * 65536.0f;
        h = (_Float16)t;
        hb[e] = h; lb[e] = (_Float16)(t - (float)h);
    }
    _Float16* hr = eh + (size_t)row * DIM;
    _Float16* lr = el + (size_t)row * DIM;
    ((half4*)hr)[lane]      = ha;
    ((half4*)lr)[lane]      = la;
    ((half4*)hr)[lane + 64] = hb;
    ((half4*)lr)[lane + 64] = lb;
}

// ---------------- kernel 3: MFMA distance GEMM + fused argmin ----------------
// Score keeps the PASSING rounding structure: s = fl( fl(sqx+sqe) - acc*2^-26 ).
// LDS layout TRANSPOSED to [kq][row] 16B chunks: fragment-read bank quad =
// tx&7 (2-way = free); staging via global_load_lds (lane-linear chunks, no
// ds_write, no VGPR round trip). blockIdx swizzle bn=hi bits: the 8 blocks
// sharing an A-tile land on ONE XCD (b mod 8 = bm mod 8).
__global__ __launch_bounds__(256) void mfma_argmin_kernel(const _Float16* __restrict__ ah,
                                                          const _Float16* __restrict__ al,
                                                          const _Float16* __restrict__ eh,
                                                          const _Float16* __restrict__ el,
                                                          const float* __restrict__ esq,
                                                          const float* __restrict__ xsq,
                                                          unsigned long long* __restrict__ packed) {
    __shared__ half8 AhT[512], AlT[512], EhT[512], ElT[512];   // [kq=c>>7][row=c&127]
    __shared__ float redv[128][2];
    __shared__ int   redi[128][2];

    const int tid = threadIdx.x;
    const int lane = tid & 63, wave = tid >> 6;
    const int wm = wave >> 1, wn = wave & 1;      // 2x2 wave grid
    const int tx = lane & 15, qd = lane >> 4;
    const int bm = blockIdx.x & 127, bn = blockIdx.x >> 7;   // XCD-aware swizzle
    const int m0 = bm * 128, c0 = bn * 128;

    // staging addresses: chunk c = it*256 + wave*64 + lane -> kq=c>>7, row=c&127
    const int rowL = (wave & 1) * 64 + lane;
    const int kqL  = wave >> 1;
    size_t offA = (size_t)(m0 + rowL) * DIM + kqL * 8;
    size_t offE = (size_t)(c0 + rowL) * DIM + kqL * 8;
    const int cb0 = wave * 64, cb1 = 256 + wave * 64;

    floatx4 acc[4][4];
    #pragma unroll
    for (int i = 0; i < 4; ++i)
        #pragma unroll
        for (int j = 0; j < 4; ++j) acc[i][j] = (floatx4){0.f, 0.f, 0.f, 0.f};

    #pragma unroll 1                               // spill guard: do not unroll K-loop
    for (int kt = 0; kt < DIM / 32; ++kt) {
        gl_lds16(ah + offA,      &AhT[cb0]);
        gl_lds16(ah + offA + 16, &AhT[cb1]);
        gl_lds16(al + offA,      &AlT[cb0]);
        gl_lds16(al + offA + 16, &AlT[cb1]);
        gl_lds16(eh + offE,      &EhT[cb0]);
        gl_lds16(eh + offE + 16, &EhT[cb1]);
        gl_lds16(el + offE,      &ElT[cb0]);
        gl_lds16(el + offE + 16, &ElT[cb1]);
        offA += 32; offE += 32;
        __syncthreads();                           // drains vmcnt -> LDS ready

        half8 fa[4], fbh[4], fbl[4];
        #pragma unroll
        for (int i = 0; i < 4; ++i)
            fa[i] = AhT[qd * 128 + wm * 64 + i * 16 + tx];
        #pragma unroll
        for (int j = 0; j < 4; ++j) {
            fbh[j] = EhT[qd * 128 + wn * 64 + j * 16 + tx];
            fbl[j] = ElT[qd * 128 + wn * 64 + j * 16 + tx];
        }
        #pragma unroll
        for (int i = 0; i < 4; ++i)
            #pragma unroll
            for (int j = 0; j < 4; ++j)
                acc[i][j] = __builtin_amdgcn_mfma_f32_16x16x32_f16(fa[i], fbh[j], acc[i][j], 0, 0, 0);
        #pragma unroll
        for (int i = 0; i < 4; ++i)
            #pragma unroll
            for (int j = 0; j < 4; ++j)
                acc[i][j] = __builtin_amdgcn_mfma_f32_16x16x32_f16(fa[i], fbl[j], acc[i][j], 0, 0, 0);
        #pragma unroll
        for (int i = 0; i < 4; ++i)                // reuse fa regs for A-lo
            fa[i] = AlT[qd * 128 + wm * 64 + i * 16 + tx];
        #pragma unroll
        for (int i = 0; i < 4; ++i)
            #pragma unroll
            for (int j = 0; j < 4; ++j)
                acc[i][j] = __builtin_amdgcn_mfma_f32_16x16x32_f16(fa[i], fbh[j], acc[i][j], 0, 0, 0);
        __syncthreads();
    }

    // ---- epilogue: scores + argmin (identical arithmetic to passing rounds) ----
    float sqe_v[4];
    #pragma unroll
    for (int j = 0; j < 4; ++j) sqe_v[j] = esq[c0 + wn * 64 + j * 16 + tx];
    #pragma unroll
    for (int i = 0; i < 4; ++i) {
        #pragma unroll
        for (int r = 0; r < 4; ++r) {
            int rl = wm * 64 + i * 16 + qd * 4 + r;        // C/D: row = qd*4+reg
            float sx = xsq[m0 + rl];
            float bvv = FLT_MAX; int bii = 0x7fffffff;
            #pragma unroll
            for (int j = 0; j < 4; ++j) {
                float S = sx + sqe_v[j];                   // fl(sqx + sqe)
                float s = S - acc[i][j][r] * (1.0f / 67108864.0f);  // fl(S - 2m)
                int c = c0 + wn * 64 + j * 16 + tx;
                if (s < bvv || (s == bvv && c < bii)) { bvv = s; bii = c; }
            }
            #pragma unroll
            for (int md = 1; md < 16; md <<= 1) {
                float ov = __shfl_xor(bvv, md, 64);
                int   oc = __shfl_xor(bii, md, 64);
                if (ov < bvv || (ov == bvv && oc < bii)) { bvv = ov; bii = oc; }
            }
            if (tx == 0) { redv[rl][wn] = bvv; redi[rl][wn] = bii; }
        }
    }
    __syncthreads();
    if (tid < 128) {
        float v0 = redv[tid][0], v1 = redv[tid][1];
        int   i0 = redi[tid][0], i1 = redi[tid][1];
        float v = (v1 < v0) ? v1 : v0;            // tie -> wn0 (smaller col)
        int   ix = (v1 < v0) ? i1 : i0;
        // scores are always positive (~512) -> float bits monotonic; lexicographic
        // (score_bits, idx) min == np.argmin first-occurrence tie-break.
        unsigned long long pk = ((unsigned long long)__float_as_uint(v) << 32)
                              | (unsigned int)ix;
        atomicMin(&packed[m0 + tid], pk);
    }
}

// ---------------- kernel 4: gather quantized + indices + loss ----------------
__global__ __launch_bounds__(256) void finalize_kernel(const float* __restrict__ A,
                                                       const float* __restrict__ E,
                                                       const unsigned long long* __restrict__ packed,
                                                       float* __restrict__ out) {
    float* q = out + 1;
    float* idxF = out + 1 + QELEMS;
    const int tid = threadIdx.x;
    const int r0 = blockIdx.x * 32;

    __shared__ int sidx[32];
    if (tid < 32) {
        int idx = (int)(unsigned int)(packed[r0 + tid] & 0xFFFFFFFFull);
        sidx[tid] = idx;
        idxF[r0 + tid] = (float)idx;
    }
    __syncthreads();

    float sacc = 0.f;
    #pragma unroll 4
    for (int it = 0; it < 16; ++it) {             // 32 rows * 128 float4 = 4096 slots
        int flat = it * 256 + tid;
        int row = flat >> 7;
        int d4  = (flat & 127) * 4;
        int idx = sidx[row];
        float4 e = *(const float4*)(E + (size_t)idx * DIM + d4);
        float4 x = *(const float4*)(A + (size_t)(r0 + row) * DIM + d4);
        *(float4*)(q + (size_t)(r0 + row) * DIM + d4) = e;
        float d0 = e.x - x.x, d1 = e.y - x.y, d2 = e.z - x.z, d3 = e.w - x.w;
        sacc += d0*d0 + d1*d1 + d2*d2 + d3*d3;
    }
    #pragma unroll
    for (int off = 32; off; off >>= 1) sacc += __shfl_down(sacc, off, 64);
    __shared__ float ps[4];
    if ((tid & 63) == 0) ps[tid >> 6] = sacc;
    __syncthreads();
    if (tid == 0)
        atomicAdd(out, (ps[0] + ps[1] + ps[2] + ps[3]) * (1.25f / (float)QELEMS));
}

extern "C" void kernel_launch(void* const* d_in, const int* in_sizes, int n_in,
                              void* d_out, int out_size, void* d_ws, size_t ws_size,
                              hipStream_t stream) {
    const float* A = (const float*)d_in[0];   // inputs (64,256,512)
    const float* E = (const float*)d_in[1];   // emb_weight (1024,512)
    float* out = (float*)d_out;

    unsigned long long* packed = (unsigned long long*)d_ws;     // 16384 u64 (8B-aligned first)
    float*    esq  = (float*)(packed + NROWS);                  // 1024
    float*    xsq  = esq + KC;                                  // 16384
    _Float16* eh   = (_Float16*)(xsq + NROWS);                  // 1024*512 (16B-aligned)
    _Float16* el   = eh + (size_t)KC * DIM;
    _Float16* ah   = el + (size_t)KC * DIM;                     // 16384*512
    _Float16* al   = ah + (size_t)NROWS * DIM;

    prep_a_kernel<<<NROWS / 4, 256, 0, stream>>>(A, xsq, ah, al, packed, out);
    prep_e_kernel<<<KC / 4,    256, 0, stream>>>(E, esq, eh, el);
    mfma_argmin_kernel<<<(NROWS / 128) * NSPLIT, 256, 0, stream>>>(
        ah, al, eh, el, esq, xsq, packed);
    finalize_kernel<<<NROWS / 32, 256, 0, stream>>>(A, E, packed, out);
}